// Round 1
// baseline (322.771 us; speedup 1.0000x reference)
//
#include <hip/hip_runtime.h>
#include <hip/hip_bf16.h>

typedef __bf16 bf16_t;
typedef __bf16 bf16x4 __attribute__((ext_vector_type(4)));
typedef __bf16 bf16x8 __attribute__((ext_vector_type(8)));
typedef float  f32x4  __attribute__((ext_vector_type(4)));

#define GLDS16(gp, lp) __builtin_amdgcn_global_load_lds( \
    (const __attribute__((address_space(1))) void*)(gp), \
    (__attribute__((address_space(3))) void*)(lp), 16, 0, 0)

#define MFMA16(a, b, c) __builtin_amdgcn_mfma_f32_16x16x32_bf16((a), (b), (c), 0, 0, 0)

static constexpr int kB = 2, kS = 2048, kD = 1024, kH = 16, kL = 64;
static constexpr int kM = kB * kS;       // 4096 rows
static constexpr int kNqkv = 3 * kD;     // 3072
static constexpr int kBH = kB * kH;      // 32

// ---------------------------------------------------------------------------
// K1a: cast x f32 -> bf16
// ---------------------------------------------------------------------------
__global__ void cast_x_kernel(const float* __restrict__ x, bf16_t* __restrict__ xb) {
    int i = blockIdx.x * 256 + threadIdx.x;   // 1M threads, 4 elems each
    float4 v = ((const float4*)x)[i];
    bf16x4 o;
    o[0] = (bf16_t)v.x; o[1] = (bf16_t)v.y; o[2] = (bf16_t)v.z; o[3] = (bf16_t)v.w;
    ((bf16x4*)xb)[i] = o;
}

// ---------------------------------------------------------------------------
// K1b: transpose-cast a [1024][1024] f32 weight into bf16 [N][K] (B^T layout)
// ---------------------------------------------------------------------------
__global__ void wtrans_kernel(const float* __restrict__ W, bf16_t* __restrict__ Wt) {
    __shared__ float t[32 * 33];
    const int k0 = blockIdx.x * 32, n0 = blockIdx.y * 32;
    const int tid = threadIdx.x;
#pragma unroll
    for (int i = 0; i < 4; ++i) {
        int idx = i * 256 + tid;
        int r = idx >> 5, c = idx & 31;
        t[r * 33 + c] = W[(size_t)(k0 + r) * 1024 + n0 + c];
    }
    __syncthreads();
#pragma unroll
    for (int i = 0; i < 4; ++i) {
        int idx = i * 256 + tid;
        int r = idx >> 5, c = idx & 31;     // r = n-local, c = k-local
        Wt[(size_t)(n0 + r) * 1024 + k0 + c] = (bf16_t)t[c * 33 + r];
    }
}

// ---------------------------------------------------------------------------
// K1c: RoPE cos/sin tables [S][32] f32 (device-side precompute; double math)
// ---------------------------------------------------------------------------
__global__ void rope_table_kernel(float* __restrict__ cosT, float* __restrict__ sinT) {
    int i = blockIdx.x * 256 + threadIdx.x;   // S*32 = 65536
    int s = i >> 5, j = i & 31;
    double inv = pow(10000.0, -2.0 * (double)j / 64.0);
    double ang = (double)s * inv;
    cosT[i] = (float)cos(ang);
    sinT[i] = (float)sin(ang);
}

// ---------------------------------------------------------------------------
// K2/K8: bf16 GEMM, A [M][K] x Bt [N][K] -> C [M][N].  128x128 tile, BK=32,
// 4 waves (2x2), global_load_lds width-16 staging (m97 structure).
// MODE 0: bf16 out + 3-section bias (qkv).  MODE 1: f32 out + bias (proj).
// ---------------------------------------------------------------------------
template <int MODE>
__global__ __launch_bounds__(256, 2)
void gemm_bf16(const bf16_t* __restrict__ A, const bf16_t* __restrict__ Bt,
               void* __restrict__ Cout,
               const float* __restrict__ b0, const float* __restrict__ b1,
               const float* __restrict__ b2, int Ndim, int Kdim) {
    __shared__ __align__(16) bf16_t Alds[128 * 32];
    __shared__ __align__(16) bf16_t Blds[128 * 32];
    const int tid = threadIdx.x;
    const int lane = tid & 63;
    const int wid = tid >> 6;
    const int lo = lane & 15, hi = lane >> 4;
    const int bm = blockIdx.x, bn = blockIdx.y;
    const int wr = wid >> 1, wc = wid & 1;

    // staging: 8 chunks of 1KB per matrix, 2 per wave; chunk = 16 rows x 32 cols
    const int rowS = (wid * 2) * 16 + (lane >> 2);
    const int colE = (lane & 3) * 8;
    const bf16_t* gA0 = A + (size_t)(bm * 128 + rowS) * Kdim + colE;
    const bf16_t* gA1 = gA0 + (size_t)16 * Kdim;
    const bf16_t* gB0 = Bt + (size_t)(bn * 128 + rowS) * Kdim + colE;
    const bf16_t* gB1 = gB0 + (size_t)16 * Kdim;
    bf16_t* lA0 = &Alds[(wid * 2) * 512];
    bf16_t* lA1 = &Alds[(wid * 2 + 1) * 512];
    bf16_t* lB0 = &Blds[(wid * 2) * 512];
    bf16_t* lB1 = &Blds[(wid * 2 + 1) * 512];

    f32x4 acc[4][4];
#pragma unroll
    for (int m = 0; m < 4; ++m)
#pragma unroll
        for (int n = 0; n < 4; ++n) acc[m][n] = (f32x4){0.f, 0.f, 0.f, 0.f};

    const int nk = Kdim >> 5;
    for (int kt = 0; kt < nk; ++kt) {
        const int k0 = kt * 32;
        GLDS16(gA0 + k0, lA0);
        GLDS16(gA1 + k0, lA1);
        GLDS16(gB0 + k0, lB0);
        GLDS16(gB1 + k0, lB1);
        __syncthreads();
        bf16x8 aF[4], bF[4];
#pragma unroll
        for (int m = 0; m < 4; ++m)
            aF[m] = *(const bf16x8*)&Alds[(wr * 64 + m * 16 + lo) * 32 + hi * 8];
#pragma unroll
        for (int n = 0; n < 4; ++n)
            bF[n] = *(const bf16x8*)&Blds[(wc * 64 + n * 16 + lo) * 32 + hi * 8];
#pragma unroll
        for (int m = 0; m < 4; ++m)
#pragma unroll
            for (int n = 0; n < 4; ++n)
                acc[m][n] = MFMA16(aF[m], bF[n], acc[m][n]);
        __syncthreads();
    }

    const int rbase = bm * 128 + wr * 64 + hi * 4;
    const int cbase = bn * 128 + wc * 64 + lo;
    if (MODE == 0) {
        bf16_t* C = (bf16_t*)Cout;
#pragma unroll
        for (int m = 0; m < 4; ++m)
#pragma unroll
            for (int n = 0; n < 4; ++n) {
                const int col = cbase + n * 16;
                const float bias = (col < 1024) ? b0[col]
                                 : (col < 2048) ? b1[col - 1024] : b2[col - 2048];
#pragma unroll
                for (int r = 0; r < 4; ++r) {
                    const int row = rbase + m * 16 + r;
                    C[(size_t)row * Ndim + col] = (bf16_t)(acc[m][n][r] + bias);
                }
            }
    } else {
        float* C = (float*)Cout;
#pragma unroll
        for (int m = 0; m < 4; ++m)
#pragma unroll
            for (int n = 0; n < 4; ++n) {
                const int col = cbase + n * 16;
                const float bias = b0[col];
#pragma unroll
                for (int r = 0; r < 4; ++r) {
                    const int row = rbase + m * 16 + r;
                    C[(size_t)row * Ndim + col] = acc[m][n][r] + bias;
                }
            }
    }
}

// ---------------------------------------------------------------------------
// K3: RoPE for Q,K + transpose to [BH][S][64]
// one thread per (b,s,h): 128B in per stream, 128B out
// ---------------------------------------------------------------------------
__global__ void rope_qk_kernel(const bf16_t* __restrict__ qkv,
                               const float* __restrict__ cosT,
                               const float* __restrict__ sinT,
                               bf16_t* __restrict__ Qr, bf16_t* __restrict__ Kr) {
    const int gid = blockIdx.x * 256 + threadIdx.x;  // B*S*H = 65536
    const int h = gid & 15;
    const int bs = gid >> 4;
    const int s = bs & (kS - 1);
    const int b = bs >> 11;
    const bf16_t* qp = qkv + (size_t)bs * kNqkv + h * 64;
    const bf16_t* kp = qp + 1024;
    const size_t outoff = ((size_t)(b * kH + h) * kS + s) * 64;
    bf16_t* qo = Qr + outoff;
    bf16_t* ko = Kr + outoff;
    const float* cr = cosT + s * 32;
    const float* sr = sinT + s * 32;
#pragma unroll
    for (int c = 0; c < 4; ++c) {
        bf16x8 q0 = *(const bf16x8*)(qp + c * 16);
        bf16x8 q1 = *(const bf16x8*)(qp + c * 16 + 8);
        bf16x8 k0 = *(const bf16x8*)(kp + c * 16);
        bf16x8 k1 = *(const bf16x8*)(kp + c * 16 + 8);
        bf16x8 qlo, qhi, klo, khi;
#pragma unroll
        for (int j = 0; j < 8; ++j) {
            const float cv = cr[c * 8 + j];
            const float sv = sr[c * 8 + j];
            float qa, qb2, ka, kb2;
            if (j < 4) {
                qa = (float)q0[2 * j];     qb2 = (float)q0[2 * j + 1];
                ka = (float)k0[2 * j];     kb2 = (float)k0[2 * j + 1];
            } else {
                qa = (float)q1[2 * j - 8]; qb2 = (float)q1[2 * j - 7];
                ka = (float)k1[2 * j - 8]; kb2 = (float)k1[2 * j - 7];
            }
            qlo[j] = (bf16_t)(qa * cv - qb2 * sv);
            qhi[j] = (bf16_t)(qa * sv + qb2 * cv);
            klo[j] = (bf16_t)(ka * cv - kb2 * sv);
            khi[j] = (bf16_t)(ka * sv + kb2 * cv);
        }
        *(bf16x8*)(qo + c * 8) = qlo;
        *(bf16x8*)(qo + 32 + c * 8) = qhi;
        *(bf16x8*)(ko + c * 8) = klo;
        *(bf16x8*)(ko + 32 + c * 8) = khi;
    }
}

// ---------------------------------------------------------------------------
// K4: V transpose -> VT [BH][64][S]
// ---------------------------------------------------------------------------
__global__ void vtrans_kernel(const bf16_t* __restrict__ qkv, bf16_t* __restrict__ VT) {
    __shared__ __align__(16) bf16_t t[64 * 72];
    const int st = blockIdx.x, bh = blockIdx.y;
    const int b = bh >> 4, h = bh & 15;
    const int tid = threadIdx.x;
    const int r = tid >> 2, g = tid & 3;
    const bf16_t* src = qkv + ((size_t)(b * kS + st * 64 + r)) * kNqkv + 2048 + h * 64 + g * 16;
    bf16x8 v0 = *(const bf16x8*)src;
    bf16x8 v1 = *(const bf16x8*)(src + 8);
    *(bf16x8*)&t[r * 72 + g * 16] = v0;
    *(bf16x8*)&t[r * 72 + g * 16 + 8] = v1;
    __syncthreads();
    bf16x8 o0, o1;
#pragma unroll
    for (int j = 0; j < 8; ++j) {
        o0[j] = t[(g * 16 + j) * 72 + r];
        o1[j] = t[(g * 16 + 8 + j) * 72 + r];
    }
    bf16_t* dst = VT + ((size_t)bh * 64 + r) * kS + st * 64 + g * 16;
    *(bf16x8*)dst = o0;
    *(bf16x8*)(dst + 8) = o1;
}

// ---------------------------------------------------------------------------
// K5: causal flash attention. 1 wave per block, 16 q-rows, KV tiles of 64.
// Q [BH][S][64], K [BH][S][64], VT [BH][64][S] -> attended [B][S][H*64] bf16
// ---------------------------------------------------------------------------
__global__ __launch_bounds__(64)
void attn_kernel(const bf16_t* __restrict__ Qr, const bf16_t* __restrict__ Kr,
                 const bf16_t* __restrict__ VT, bf16_t* __restrict__ attended) {
    __shared__ __align__(16) bf16_t Plds[16 * 72];
    const int qt = blockIdx.x, bh = blockIdx.y;
    const int lane = threadIdx.x;
    const int lo = lane & 15, hi = lane >> 4;
    const int qbase = qt * 16;
    const bf16_t* Q = Qr + ((size_t)bh * kS + qbase) * 64;
    const bf16_t* Kp = Kr + (size_t)bh * kS * 64;
    const bf16_t* Vp = VT + (size_t)bh * 64 * kS;

    const bf16x8 aQ0 = *(const bf16x8*)&Q[lo * 64 + hi * 8];
    const bf16x8 aQ1 = *(const bf16x8*)&Q[lo * 64 + 32 + hi * 8];

    f32x4 O[4];
#pragma unroll
    for (int dt = 0; dt < 4; ++dt) O[dt] = (f32x4){0.f, 0.f, 0.f, 0.f};
    float m_run[4], l_run[4];
#pragma unroll
    for (int r = 0; r < 4; ++r) { m_run[r] = -1e30f; l_run[r] = 0.f; }

    const int ntiles = qbase / 64 + 1;
    for (int t = 0; t < ntiles; ++t) {
        const int kv0 = t * 64;
        f32x4 sacc[4];
#pragma unroll
        for (int ct = 0; ct < 4; ++ct) sacc[ct] = (f32x4){0.f, 0.f, 0.f, 0.f};
#pragma unroll
        for (int ct = 0; ct < 4; ++ct) {
            const bf16x8 bK0 = *(const bf16x8*)&Kp[(size_t)(kv0 + ct * 16 + lo) * 64 + hi * 8];
            const bf16x8 bK1 = *(const bf16x8*)&Kp[(size_t)(kv0 + ct * 16 + lo) * 64 + 32 + hi * 8];
            sacc[ct] = MFMA16(aQ0, bK0, sacc[ct]);
            sacc[ct] = MFMA16(aQ1, bK1, sacc[ct]);
        }
        float p[4][4];
        float pmax[4] = {-1e30f, -1e30f, -1e30f, -1e30f};
        const bool edge = (t == ntiles - 1);
#pragma unroll
        for (int ct = 0; ct < 4; ++ct)
#pragma unroll
            for (int r = 0; r < 4; ++r) {
                float sv = sacc[ct][r] * 0.125f;
                if (edge) {
                    const int kvg = kv0 + ct * 16 + lo;
                    const int qg = qbase + hi * 4 + r;
                    if (kvg > qg) sv = -1e30f;
                }
                p[ct][r] = sv;
                pmax[r] = fmaxf(pmax[r], sv);
            }
#pragma unroll
        for (int off = 1; off < 16; off <<= 1)
#pragma unroll
            for (int r = 0; r < 4; ++r)
                pmax[r] = fmaxf(pmax[r], __shfl_xor(pmax[r], off, 64));
        float alpha[4], psum[4];
#pragma unroll
        for (int r = 0; r < 4; ++r) {
            const float mn = fmaxf(m_run[r], pmax[r]);
            alpha[r] = __expf(m_run[r] - mn);
            m_run[r] = mn;
            psum[r] = 0.f;
        }
#pragma unroll
        for (int ct = 0; ct < 4; ++ct)
#pragma unroll
            for (int r = 0; r < 4; ++r) {
                const float e = __expf(p[ct][r] - m_run[r]);
                p[ct][r] = e;
                psum[r] += e;
            }
#pragma unroll
        for (int off = 1; off < 16; off <<= 1)
#pragma unroll
            for (int r = 0; r < 4; ++r)
                psum[r] += __shfl_xor(psum[r], off, 64);
#pragma unroll
        for (int r = 0; r < 4; ++r) l_run[r] = l_run[r] * alpha[r] + psum[r];
#pragma unroll
        for (int dt = 0; dt < 4; ++dt)
#pragma unroll
            for (int r = 0; r < 4; ++r) O[dt][r] *= alpha[r];
        // P -> LDS (bf16), then A-frag reads
#pragma unroll
        for (int ct = 0; ct < 4; ++ct)
#pragma unroll
            for (int r = 0; r < 4; ++r)
                Plds[(hi * 4 + r) * 72 + ct * 16 + lo] = (bf16_t)p[ct][r];
        __syncthreads();
        const bf16x8 aP0 = *(const bf16x8*)&Plds[lo * 72 + hi * 8];
        const bf16x8 aP1 = *(const bf16x8*)&Plds[lo * 72 + 32 + hi * 8];
        __syncthreads();
#pragma unroll
        for (int dt = 0; dt < 4; ++dt) {
            const bf16x8 bV0 = *(const bf16x8*)&Vp[(size_t)(dt * 16 + lo) * kS + kv0 + hi * 8];
            const bf16x8 bV1 = *(const bf16x8*)&Vp[(size_t)(dt * 16 + lo) * kS + kv0 + 32 + hi * 8];
            O[dt] = MFMA16(aP0, bV0, O[dt]);
            O[dt] = MFMA16(aP1, bV1, O[dt]);
        }
    }
    const int b = bh >> 4, h = bh & 15;
#pragma unroll
    for (int dt = 0; dt < 4; ++dt)
#pragma unroll
        for (int r = 0; r < 4; ++r) {
            const float v = O[dt][r] / l_run[r];
            const int row = qbase + hi * 4 + r;
            attended[((size_t)(b * kS + row)) * kD + h * 64 + dt * 16 + lo] = (bf16_t)v;
        }
}

// ---------------------------------------------------------------------------
extern "C" void kernel_launch(void* const* d_in, const int* in_sizes, int n_in,
                              void* d_out, int out_size, void* d_ws, size_t ws_size,
                              hipStream_t stream) {
    const float* x  = (const float*)d_in[0];
    const float* Wq = (const float*)d_in[1];
    const float* bq = (const float*)d_in[2];
    const float* Wk = (const float*)d_in[3];
    const float* bk = (const float*)d_in[4];
    const float* Wv = (const float*)d_in[5];
    const float* bv = (const float*)d_in[6];
    const float* Wo = (const float*)d_in[7];
    const float* bo = (const float*)d_in[8];
    float* out = (float*)d_out;

    char* ws = (char*)d_ws;
    size_t off = 0;
    auto carve = [&](size_t bytes) -> char* {
        char* p = ws + off;
        off += (bytes + 255) & ~(size_t)255;
        return p;
    };
    bf16_t* xb    = (bf16_t*)carve((size_t)kM * kD * 2);          // 8 MB
    bf16_t* WqkvT = (bf16_t*)carve((size_t)kNqkv * kD * 2);       // 6 MB
    bf16_t* WoT   = (bf16_t*)carve((size_t)kD * kD * 2);          // 2 MB
    float*  cosT  = (float*)carve((size_t)kS * 32 * 4);
    float*  sinT  = (float*)carve((size_t)kS * 32 * 4);
    bf16_t* qkv   = (bf16_t*)carve((size_t)kM * kNqkv * 2);       // 24 MB
    bf16_t* Qr    = (bf16_t*)carve((size_t)kBH * kS * 64 * 2);    // 8 MB
    bf16_t* Kr    = (bf16_t*)carve((size_t)kBH * kS * 64 * 2);    // 8 MB
    bf16_t* VT    = (bf16_t*)carve((size_t)kBH * kS * 64 * 2);    // 8 MB
    bf16_t* att   = (bf16_t*)carve((size_t)kM * kD * 2);          // 8 MB

    cast_x_kernel<<<(kM * kD) / (256 * 4), 256, 0, stream>>>(x, xb);
    wtrans_kernel<<<dim3(32, 32), 256, 0, stream>>>(Wq, WqkvT);
    wtrans_kernel<<<dim3(32, 32), 256, 0, stream>>>(Wk, WqkvT + (size_t)1024 * 1024);
    wtrans_kernel<<<dim3(32, 32), 256, 0, stream>>>(Wv, WqkvT + (size_t)2048 * 1024);
    wtrans_kernel<<<dim3(32, 32), 256, 0, stream>>>(Wo, WoT);
    rope_table_kernel<<<(kS * 32) / 256, 256, 0, stream>>>(cosT, sinT);

    gemm_bf16<0><<<dim3(kM / 128, kNqkv / 128), 256, 0, stream>>>(
        xb, WqkvT, qkv, bq, bk, bv, kNqkv, kD);

    rope_qk_kernel<<<(kB * kS * kH) / 256, 256, 0, stream>>>(qkv, cosT, sinT, Qr, Kr);
    vtrans_kernel<<<dim3(kS / 64, kBH), 256, 0, stream>>>(qkv, VT);

    attn_kernel<<<dim3(kS / 16, kBH), 64, 0, stream>>>(Qr, Kr, VT, att);

    gemm_bf16<1><<<dim3(kM / 128, kD / 128), 256, 0, stream>>>(
        att, WoT, out, bo, nullptr, nullptr, kD, kD);
}

// Round 2
// 211.504 us; speedup vs baseline: 1.5261x; 1.5261x over previous
//
#include <hip/hip_runtime.h>
#include <hip/hip_bf16.h>

typedef __bf16 bf16_t;
typedef __bf16 bf16x4 __attribute__((ext_vector_type(4)));
typedef __bf16 bf16x8 __attribute__((ext_vector_type(8)));
typedef float  f32x4  __attribute__((ext_vector_type(4)));

#define GLDS16(gp, lp) __builtin_amdgcn_global_load_lds( \
    (const __attribute__((address_space(1))) void*)(gp), \
    (__attribute__((address_space(3))) void*)(lp), 16, 0, 0)

#define MFMA16(a, b, c) __builtin_amdgcn_mfma_f32_16x16x32_bf16((a), (b), (c), 0, 0, 0)

static constexpr int kB = 2, kS = 2048, kD = 1024, kH = 16, kL = 64;
static constexpr int kM = kB * kS;       // 4096 rows
static constexpr int kNqkv = 3 * kD;     // 3072
static constexpr int kBH = kB * kH;      // 32

// ---------------------------------------------------------------------------
// K1a: cast x f32 -> bf16
// ---------------------------------------------------------------------------
__global__ void cast_x_kernel(const float* __restrict__ x, bf16_t* __restrict__ xb) {
    int i = blockIdx.x * 256 + threadIdx.x;
    float4 v = ((const float4*)x)[i];
    bf16x4 o;
    o[0] = (bf16_t)v.x; o[1] = (bf16_t)v.y; o[2] = (bf16_t)v.z; o[3] = (bf16_t)v.w;
    ((bf16x4*)xb)[i] = o;
}

// ---------------------------------------------------------------------------
// K1b: transpose-cast a [1024][1024] f32 weight into bf16 [N][K] (B^T layout)
// ---------------------------------------------------------------------------
__global__ void wtrans_kernel(const float* __restrict__ W, bf16_t* __restrict__ Wt) {
    __shared__ float t[32 * 33];
    const int k0 = blockIdx.x * 32, n0 = blockIdx.y * 32;
    const int tid = threadIdx.x;
#pragma unroll
    for (int i = 0; i < 4; ++i) {
        int idx = i * 256 + tid;
        int r = idx >> 5, c = idx & 31;
        t[r * 33 + c] = W[(size_t)(k0 + r) * 1024 + n0 + c];
    }
    __syncthreads();
#pragma unroll
    for (int i = 0; i < 4; ++i) {
        int idx = i * 256 + tid;
        int r = idx >> 5, c = idx & 31;
        Wt[(size_t)(n0 + r) * 1024 + k0 + c] = (bf16_t)t[c * 33 + r];
    }
}

// ---------------------------------------------------------------------------
// K1c: RoPE cos/sin tables [S][32] f32
// ---------------------------------------------------------------------------
__global__ void rope_table_kernel(float* __restrict__ cosT, float* __restrict__ sinT) {
    int i = blockIdx.x * 256 + threadIdx.x;
    int s = i >> 5, j = i & 31;
    double inv = pow(10000.0, -2.0 * (double)j / 64.0);
    double ang = (double)s * inv;
    cosT[i] = (float)cos(ang);
    sinT[i] = (float)sin(ang);
}

// ---------------------------------------------------------------------------
// K2/K8: bf16 GEMM (m97 structure), unchanged from round 1
// ---------------------------------------------------------------------------
template <int MODE>
__global__ __launch_bounds__(256, 2)
void gemm_bf16(const bf16_t* __restrict__ A, const bf16_t* __restrict__ Bt,
               void* __restrict__ Cout,
               const float* __restrict__ b0, const float* __restrict__ b1,
               const float* __restrict__ b2, int Ndim, int Kdim) {
    __shared__ __align__(16) bf16_t Alds[128 * 32];
    __shared__ __align__(16) bf16_t Blds[128 * 32];
    const int tid = threadIdx.x;
    const int lane = tid & 63;
    const int wid = tid >> 6;
    const int lo = lane & 15, hi = lane >> 4;
    const int bm = blockIdx.x, bn = blockIdx.y;
    const int wr = wid >> 1, wc = wid & 1;

    const int rowS = (wid * 2) * 16 + (lane >> 2);
    const int colE = (lane & 3) * 8;
    const bf16_t* gA0 = A + (size_t)(bm * 128 + rowS) * Kdim + colE;
    const bf16_t* gA1 = gA0 + (size_t)16 * Kdim;
    const bf16_t* gB0 = Bt + (size_t)(bn * 128 + rowS) * Kdim + colE;
    const bf16_t* gB1 = gB0 + (size_t)16 * Kdim;
    bf16_t* lA0 = &Alds[(wid * 2) * 512];
    bf16_t* lA1 = &Alds[(wid * 2 + 1) * 512];
    bf16_t* lB0 = &Blds[(wid * 2) * 512];
    bf16_t* lB1 = &Blds[(wid * 2 + 1) * 512];

    f32x4 acc[4][4];
#pragma unroll
    for (int m = 0; m < 4; ++m)
#pragma unroll
        for (int n = 0; n < 4; ++n) acc[m][n] = (f32x4){0.f, 0.f, 0.f, 0.f};

    const int nk = Kdim >> 5;
    for (int kt = 0; kt < nk; ++kt) {
        const int k0 = kt * 32;
        GLDS16(gA0 + k0, lA0);
        GLDS16(gA1 + k0, lA1);
        GLDS16(gB0 + k0, lB0);
        GLDS16(gB1 + k0, lB1);
        __syncthreads();
        bf16x8 aF[4], bF[4];
#pragma unroll
        for (int m = 0; m < 4; ++m)
            aF[m] = *(const bf16x8*)&Alds[(wr * 64 + m * 16 + lo) * 32 + hi * 8];
#pragma unroll
        for (int n = 0; n < 4; ++n)
            bF[n] = *(const bf16x8*)&Blds[(wc * 64 + n * 16 + lo) * 32 + hi * 8];
#pragma unroll
        for (int m = 0; m < 4; ++m)
#pragma unroll
            for (int n = 0; n < 4; ++n)
                acc[m][n] = MFMA16(aF[m], bF[n], acc[m][n]);
        __syncthreads();
    }

    const int rbase = bm * 128 + wr * 64 + hi * 4;
    const int cbase = bn * 128 + wc * 64 + lo;
    if (MODE == 0) {
        bf16_t* C = (bf16_t*)Cout;
#pragma unroll
        for (int m = 0; m < 4; ++m)
#pragma unroll
            for (int n = 0; n < 4; ++n) {
                const int col = cbase + n * 16;
                const float bias = (col < 1024) ? b0[col]
                                 : (col < 2048) ? b1[col - 1024] : b2[col - 2048];
#pragma unroll
                for (int r = 0; r < 4; ++r) {
                    const int row = rbase + m * 16 + r;
                    C[(size_t)row * Ndim + col] = (bf16_t)(acc[m][n][r] + bias);
                }
            }
    } else {
        float* C = (float*)Cout;
#pragma unroll
        for (int m = 0; m < 4; ++m)
#pragma unroll
            for (int n = 0; n < 4; ++n) {
                const int col = cbase + n * 16;
                const float bias = b0[col];
#pragma unroll
                for (int r = 0; r < 4; ++r) {
                    const int row = rbase + m * 16 + r;
                    C[(size_t)row * Ndim + col] = acc[m][n][r] + bias;
                }
            }
    }
}

// ---------------------------------------------------------------------------
// K3: RoPE for Q,K + transpose to [BH][S][64].
// Block = one (s-tile of 64) x (b,h); 4 threads per row (16 elems each).
// K rows written chunk-swizzled: 16B chunk c -> c ^ (s&7)  (for LDS bank
// balance in attn; Q stays linear).
// ---------------------------------------------------------------------------
__global__ __launch_bounds__(256)
void rope_qk_kernel(const bf16_t* __restrict__ qkv,
                    const float* __restrict__ cosT,
                    const float* __restrict__ sinT,
                    bf16_t* __restrict__ Qr, bf16_t* __restrict__ Kr) {
    const int st = blockIdx.x, bh = blockIdx.y;
    const int b = bh >> 4, h = bh & 15;
    const int tid = threadIdx.x;
    const int r = tid >> 2;          // row in tile (0..63)
    const int part = tid & 3;        // 16-elem part of the 64-dim head
    const int s = st * 64 + r;
    const int bs = b * kS + s;
    const bf16_t* qp = qkv + (size_t)bs * kNqkv + h * 64 + part * 16;
    const bf16_t* kp = qp + 1024;
    const size_t outoff = ((size_t)(b * kH + h) * kS + s) * 64;
    bf16_t* qo = Qr + outoff;
    char*   kob = (char*)(Kr + outoff);
    const float* cr = cosT + s * 32 + part * 8;
    const float* sr = sinT + s * 32 + part * 8;

    bf16x8 q0 = *(const bf16x8*)qp;
    bf16x8 q1 = *(const bf16x8*)(qp + 8);
    bf16x8 k0 = *(const bf16x8*)kp;
    bf16x8 k1 = *(const bf16x8*)(kp + 8);
    bf16x8 qlo, qhi, klo, khi;
#pragma unroll
    for (int j = 0; j < 8; ++j) {
        const float cv = cr[j];
        const float sv = sr[j];
        float qa, qb2, ka, kb2;
        if (j < 4) {
            qa = (float)q0[2 * j];     qb2 = (float)q0[2 * j + 1];
            ka = (float)k0[2 * j];     kb2 = (float)k0[2 * j + 1];
        } else {
            qa = (float)q1[2 * j - 8]; qb2 = (float)q1[2 * j - 7];
            ka = (float)k1[2 * j - 8]; kb2 = (float)k1[2 * j - 7];
        }
        qlo[j] = (bf16_t)(qa * cv - qb2 * sv);
        qhi[j] = (bf16_t)(qa * sv + qb2 * cv);
        klo[j] = (bf16_t)(ka * cv - kb2 * sv);
        khi[j] = (bf16_t)(ka * sv + kb2 * cv);
    }
    *(bf16x8*)(qo + part * 8)      = qlo;
    *(bf16x8*)(qo + 32 + part * 8) = qhi;
    const int sw = s & 7;
    *(bf16x8*)(kob + (((part)     ^ sw) << 4)) = klo;
    *(bf16x8*)(kob + (((part + 4) ^ sw) << 4)) = khi;
}

// ---------------------------------------------------------------------------
// K4: V transpose -> VT [BH][64][S], chunk-swizzled within each 64-col tile:
// 16B chunk c -> c ^ (d&7)
// ---------------------------------------------------------------------------
__global__ void vtrans_kernel(const bf16_t* __restrict__ qkv, bf16_t* __restrict__ VT) {
    __shared__ __align__(16) bf16_t t[64 * 72];
    const int st = blockIdx.x, bh = blockIdx.y;
    const int b = bh >> 4, h = bh & 15;
    const int tid = threadIdx.x;
    const int r = tid >> 2, g = tid & 3;
    const bf16_t* src = qkv + ((size_t)(b * kS + st * 64 + r)) * kNqkv + 2048 + h * 64 + g * 16;
    bf16x8 v0 = *(const bf16x8*)src;
    bf16x8 v1 = *(const bf16x8*)(src + 8);
    *(bf16x8*)&t[r * 72 + g * 16] = v0;
    *(bf16x8*)&t[r * 72 + g * 16 + 8] = v1;
    __syncthreads();
    bf16x8 o0, o1;
#pragma unroll
    for (int j = 0; j < 8; ++j) {
        o0[j] = t[(g * 16 + j) * 72 + r];
        o1[j] = t[(g * 16 + 8 + j) * 72 + r];
    }
    // row r is the d-index; store into s-tile st with swizzled 16B chunks
    char* dstb = (char*)(VT + ((size_t)bh * 64 + r) * kS) + st * 128;
    const int sw = r & 7;
    *(bf16x8*)(dstb + (((g * 2)     ^ sw) << 4)) = o0;
    *(bf16x8*)(dstb + (((g * 2 + 1) ^ sw) << 4)) = o1;
}

// ---------------------------------------------------------------------------
// K5: causal flash attention v2.
// 4 waves/block, 64 q-rows/block (16 per wave), KV tiles of 64 staged in LDS
// via global_load_lds, double-buffered. K/V tiles are chunk-swizzled
// (written swizzled in global, read with matching XOR). log2-domain softmax.
// ---------------------------------------------------------------------------
__global__ __launch_bounds__(256, 3)
void attn_kernel(const bf16_t* __restrict__ Qr, const bf16_t* __restrict__ Kr,
                 const bf16_t* __restrict__ VT, bf16_t* __restrict__ attended) {
    __shared__ __align__(16) bf16_t Klds[2][64 * 64];
    __shared__ __align__(16) bf16_t Vlds[2][64 * 64];
    __shared__ __align__(16) bf16_t Plds[4][16 * 72];
    const int qt = blockIdx.x, bh = blockIdx.y;
    const int tid = threadIdx.x;
    const int lane = tid & 63, wid = tid >> 6;
    const int lo = lane & 15, hi = lane >> 4;
    const int qbase = qt * 64;
    const int q0 = qbase + wid * 16;

    const char* Kg = (const char*)(Kr + (size_t)bh * kS * 64);
    const char* Vg = (const char*)(VT + (size_t)bh * 64 * kS);
    const bf16_t* Q = Qr + (size_t)bh * kS * 64;

    const bf16x8 aQ0 = *(const bf16x8*)&Q[(size_t)(q0 + lo) * 64 + hi * 8];
    const bf16x8 aQ1 = *(const bf16x8*)&Q[(size_t)(q0 + lo) * 64 + 32 + hi * 8];

    bf16_t* Pl = &Plds[wid][0];

    f32x4 O[4];
#pragma unroll
    for (int dt = 0; dt < 4; ++dt) O[dt] = (f32x4){0.f, 0.f, 0.f, 0.f};
    float m_run[4], l_run[4];
#pragma unroll
    for (int r = 0; r < 4; ++r) { m_run[r] = -3e38f; l_run[r] = 0.f; }

    const int ntiles = qt + 1;

    auto stage = [&](int buf, int t) {
        char* Kl = (char*)&Klds[buf][0];
        char* Vl = (char*)&Vlds[buf][0];
        const size_t kb = (size_t)t * 128 * 64;   // K tile byte offset (contiguous)
        const int vcol = t * 128;                 // V tile col byte offset
#pragma unroll
        for (int j = 0; j < 2; ++j) {
            const int seg = wid * 2 + j;          // 1KB segments, 8 per tile
            GLDS16(Kg + kb + seg * 1024 + lane * 16, Kl + seg * 1024);
            const int row = seg * 8 + (lane >> 3);
            GLDS16(Vg + (size_t)row * (kS * 2) + vcol + (lane & 7) * 16, Vl + seg * 1024);
        }
    };

    stage(0, 0);
    int cur = 0;
    const float kScale = 0.125f * 1.44269504f;   // 1/sqrt(64) * log2(e)

    for (int t = 0; t < ntiles; ++t) {
        __syncthreads();                          // staged buf[cur] visible
        if (t + 1 < ntiles) stage(cur ^ 1, t + 1);
        const char* Kb = (const char*)&Klds[cur][0];
        const char* Vb = (const char*)&Vlds[cur][0];

        // ---- QK^T ----
        f32x4 sacc[4];
#pragma unroll
        for (int ct = 0; ct < 4; ++ct) sacc[ct] = (f32x4){0.f, 0.f, 0.f, 0.f};
#pragma unroll
        for (int ct = 0; ct < 4; ++ct) {
            const int rr = ct * 16 + lo;
            const bf16x8 bK0 = *(const bf16x8*)(Kb + rr * 128 + (((hi)     ^ (rr & 7)) << 4));
            const bf16x8 bK1 = *(const bf16x8*)(Kb + rr * 128 + (((hi + 4) ^ (rr & 7)) << 4));
            sacc[ct] = MFMA16(aQ0, bK0, sacc[ct]);
            sacc[ct] = MFMA16(aQ1, bK1, sacc[ct]);
        }

        // ---- softmax (log2 domain) ----
        const bool edge = (t == ntiles - 1);
        const int kv0 = t * 64;
        float p[4][4];
        float pmax[4] = {-3e38f, -3e38f, -3e38f, -3e38f};
#pragma unroll
        for (int ct = 0; ct < 4; ++ct)
#pragma unroll
            for (int r = 0; r < 4; ++r) {
                float sv = sacc[ct][r] * kScale;
                if (edge && (kv0 + ct * 16 + lo > q0 + hi * 4 + r)) sv = -3e38f;
                p[ct][r] = sv;
                pmax[r] = fmaxf(pmax[r], sv);
            }
#pragma unroll
        for (int off = 1; off < 16; off <<= 1)
#pragma unroll
            for (int r = 0; r < 4; ++r)
                pmax[r] = fmaxf(pmax[r], __shfl_xor(pmax[r], off, 64));
        float alpha[4], psum[4];
#pragma unroll
        for (int r = 0; r < 4; ++r) {
            const float mn = fmaxf(m_run[r], pmax[r]);
            alpha[r] = exp2f(m_run[r] - mn);
            m_run[r] = mn;
            psum[r] = 0.f;
        }
#pragma unroll
        for (int ct = 0; ct < 4; ++ct)
#pragma unroll
            for (int r = 0; r < 4; ++r) {
                const float e = exp2f(p[ct][r] - m_run[r]);
                p[ct][r] = e;
                psum[r] += e;
            }
#pragma unroll
        for (int off = 1; off < 16; off <<= 1)
#pragma unroll
            for (int r = 0; r < 4; ++r)
                psum[r] += __shfl_xor(psum[r], off, 64);
#pragma unroll
        for (int r = 0; r < 4; ++r) l_run[r] = l_run[r] * alpha[r] + psum[r];
#pragma unroll
        for (int dt = 0; dt < 4; ++dt)
#pragma unroll
            for (int r = 0; r < 4; ++r) O[dt][r] *= alpha[r];

        // ---- P -> LDS (per-wave buffer), A-frag reads ----
#pragma unroll
        for (int ct = 0; ct < 4; ++ct)
#pragma unroll
            for (int r = 0; r < 4; ++r)
                Pl[(hi * 4 + r) * 72 + ct * 16 + lo] = (bf16_t)p[ct][r];
        const bf16x8 aP0 = *(const bf16x8*)&Pl[lo * 72 + hi * 8];
        const bf16x8 aP1 = *(const bf16x8*)&Pl[lo * 72 + 32 + hi * 8];

        // ---- PV ----
#pragma unroll
        for (int dt = 0; dt < 4; ++dt) {
            const int rr = dt * 16 + lo;
            const bf16x8 bV0 = *(const bf16x8*)(Vb + rr * 128 + (((hi)     ^ (rr & 7)) << 4));
            const bf16x8 bV1 = *(const bf16x8*)(Vb + rr * 128 + (((hi + 4) ^ (rr & 7)) << 4));
            O[dt] = MFMA16(aP0, bV0, O[dt]);
            O[dt] = MFMA16(aP1, bV1, O[dt]);
        }
        cur ^= 1;
    }

    // ---- epilogue ----
    const int b = bh >> 4, h = bh & 15;
    float inv[4];
#pragma unroll
    for (int r = 0; r < 4; ++r) inv[r] = 1.0f / l_run[r];
#pragma unroll
    for (int dt = 0; dt < 4; ++dt)
#pragma unroll
        for (int r = 0; r < 4; ++r) {
            const int row = q0 + hi * 4 + r;
            attended[((size_t)(b * kS + row)) * kD + h * 64 + dt * 16 + lo] =
                (bf16_t)(O[dt][r] * inv[r]);
        }
}

// ---------------------------------------------------------------------------
extern "C" void kernel_launch(void* const* d_in, const int* in_sizes, int n_in,
                              void* d_out, int out_size, void* d_ws, size_t ws_size,
                              hipStream_t stream) {
    const float* x  = (const float*)d_in[0];
    const float* Wq = (const float*)d_in[1];
    const float* bq = (const float*)d_in[2];
    const float* Wk = (const float*)d_in[3];
    const float* bk = (const float*)d_in[4];
    const float* Wv = (const float*)d_in[5];
    const float* bv = (const float*)d_in[6];
    const float* Wo = (const float*)d_in[7];
    const float* bo = (const float*)d_in[8];
    float* out = (float*)d_out;

    char* ws = (char*)d_ws;
    size_t off = 0;
    auto carve = [&](size_t bytes) -> char* {
        char* p = ws + off;
        off += (bytes + 255) & ~(size_t)255;
        return p;
    };
    bf16_t* xb    = (bf16_t*)carve((size_t)kM * kD * 2);
    bf16_t* WqkvT = (bf16_t*)carve((size_t)kNqkv * kD * 2);
    bf16_t* WoT   = (bf16_t*)carve((size_t)kD * kD * 2);
    float*  cosT  = (float*)carve((size_t)kS * 32 * 4);
    float*  sinT  = (float*)carve((size_t)kS * 32 * 4);
    bf16_t* qkv   = (bf16_t*)carve((size_t)kM * kNqkv * 2);
    bf16_t* Qr    = (bf16_t*)carve((size_t)kBH * kS * 64 * 2);
    bf16_t* Kr    = (bf16_t*)carve((size_t)kBH * kS * 64 * 2);
    bf16_t* VT    = (bf16_t*)carve((size_t)kBH * kS * 64 * 2);
    bf16_t* att   = (bf16_t*)carve((size_t)kM * kD * 2);

    cast_x_kernel<<<(kM * kD) / (256 * 4), 256, 0, stream>>>(x, xb);
    wtrans_kernel<<<dim3(32, 32), 256, 0, stream>>>(Wq, WqkvT);
    wtrans_kernel<<<dim3(32, 32), 256, 0, stream>>>(Wk, WqkvT + (size_t)1024 * 1024);
    wtrans_kernel<<<dim3(32, 32), 256, 0, stream>>>(Wv, WqkvT + (size_t)2048 * 1024);
    wtrans_kernel<<<dim3(32, 32), 256, 0, stream>>>(Wo, WoT);
    rope_table_kernel<<<(kS * 32) / 256, 256, 0, stream>>>(cosT, sinT);

    gemm_bf16<0><<<dim3(kM / 128, kNqkv / 128), 256, 0, stream>>>(
        xb, WqkvT, qkv, bq, bk, bv, kNqkv, kD);

    rope_qk_kernel<<<dim3(kS / 64, kBH), 256, 0, stream>>>(qkv, cosT, sinT, Qr, Kr);
    vtrans_kernel<<<dim3(kS / 64, kBH), 256, 0, stream>>>(qkv, VT);

    attn_kernel<<<dim3(kS / 64, kBH), 256, 0, stream>>>(Qr, Kr, VT, att);

    gemm_bf16<1><<<dim3(kM / 128, kD / 128), 256, 0, stream>>>(
        att, WoT, out, bo, nullptr, nullptr, kD, kD);
}

// Round 3
// 166.528 us; speedup vs baseline: 1.9382x; 1.2701x over previous
//
#include <hip/hip_runtime.h>
#include <hip/hip_bf16.h>

typedef __bf16 bf16_t;
typedef __bf16 bf16x4 __attribute__((ext_vector_type(4)));
typedef __bf16 bf16x8 __attribute__((ext_vector_type(8)));
typedef float  f32x4  __attribute__((ext_vector_type(4)));

#define GLDS16(gp, lp) __builtin_amdgcn_global_load_lds( \
    (const __attribute__((address_space(1))) void*)(gp), \
    (__attribute__((address_space(3))) void*)(lp), 16, 0, 0)

#define MFMA16(a, b, c) __builtin_amdgcn_mfma_f32_16x16x32_bf16((a), (b), (c), 0, 0, 0)

static constexpr int kB = 2, kS = 2048, kD = 1024, kH = 16, kL = 64;
static constexpr int kM = kB * kS;       // 4096 rows
static constexpr int kNqkv = 3 * kD;     // 3072
static constexpr int kBH = kB * kH;      // 32

// ---------------------------------------------------------------------------
// K1a: cast x f32 -> bf16
// ---------------------------------------------------------------------------
__global__ void cast_x_kernel(const float* __restrict__ x, bf16_t* __restrict__ xb) {
    int i = blockIdx.x * 256 + threadIdx.x;
    float4 v = ((const float4*)x)[i];
    bf16x4 o;
    o[0] = (bf16_t)v.x; o[1] = (bf16_t)v.y; o[2] = (bf16_t)v.z; o[3] = (bf16_t)v.w;
    ((bf16x4*)xb)[i] = o;
}

// ---------------------------------------------------------------------------
// K1b: transpose-cast a [1024][1024] f32 weight into bf16 [N][K] (B^T layout)
// ---------------------------------------------------------------------------
__global__ void wtrans_kernel(const float* __restrict__ W, bf16_t* __restrict__ Wt) {
    __shared__ float t[32 * 33];
    const int k0 = blockIdx.x * 32, n0 = blockIdx.y * 32;
    const int tid = threadIdx.x;
#pragma unroll
    for (int i = 0; i < 4; ++i) {
        int idx = i * 256 + tid;
        int r = idx >> 5, c = idx & 31;
        t[r * 33 + c] = W[(size_t)(k0 + r) * 1024 + n0 + c];
    }
    __syncthreads();
#pragma unroll
    for (int i = 0; i < 4; ++i) {
        int idx = i * 256 + tid;
        int r = idx >> 5, c = idx & 31;
        Wt[(size_t)(n0 + r) * 1024 + k0 + c] = (bf16_t)t[c * 33 + r];
    }
}

// ---------------------------------------------------------------------------
// K1c: RoPE cos/sin tables [S][32] f32
// ---------------------------------------------------------------------------
__global__ void rope_table_kernel(float* __restrict__ cosT, float* __restrict__ sinT) {
    int i = blockIdx.x * 256 + threadIdx.x;
    int s = i >> 5, j = i & 31;
    double inv = pow(10000.0, -2.0 * (double)j / 64.0);
    double ang = (double)s * inv;
    cosT[i] = (float)cos(ang);
    sinT[i] = (float)sin(ang);
}

// ---------------------------------------------------------------------------
// K2/K8: bf16 GEMM (m97 structure)
// ---------------------------------------------------------------------------
template <int MODE>
__global__ __launch_bounds__(256, 2)
void gemm_bf16(const bf16_t* __restrict__ A, const bf16_t* __restrict__ Bt,
               void* __restrict__ Cout,
               const float* __restrict__ b0, const float* __restrict__ b1,
               const float* __restrict__ b2, int Ndim, int Kdim) {
    __shared__ __align__(16) bf16_t Alds[128 * 32];
    __shared__ __align__(16) bf16_t Blds[128 * 32];
    const int tid = threadIdx.x;
    const int lane = tid & 63;
    const int wid = tid >> 6;
    const int lo = lane & 15, hi = lane >> 4;
    const int bm = blockIdx.x, bn = blockIdx.y;
    const int wr = wid >> 1, wc = wid & 1;

    const int rowS = (wid * 2) * 16 + (lane >> 2);
    const int colE = (lane & 3) * 8;
    const bf16_t* gA0 = A + (size_t)(bm * 128 + rowS) * Kdim + colE;
    const bf16_t* gA1 = gA0 + (size_t)16 * Kdim;
    const bf16_t* gB0 = Bt + (size_t)(bn * 128 + rowS) * Kdim + colE;
    const bf16_t* gB1 = gB0 + (size_t)16 * Kdim;
    bf16_t* lA0 = &Alds[(wid * 2) * 512];
    bf16_t* lA1 = &Alds[(wid * 2 + 1) * 512];
    bf16_t* lB0 = &Blds[(wid * 2) * 512];
    bf16_t* lB1 = &Blds[(wid * 2 + 1) * 512];

    f32x4 acc[4][4];
#pragma unroll
    for (int m = 0; m < 4; ++m)
#pragma unroll
        for (int n = 0; n < 4; ++n) acc[m][n] = (f32x4){0.f, 0.f, 0.f, 0.f};

    const int nk = Kdim >> 5;
    for (int kt = 0; kt < nk; ++kt) {
        const int k0 = kt * 32;
        GLDS16(gA0 + k0, lA0);
        GLDS16(gA1 + k0, lA1);
        GLDS16(gB0 + k0, lB0);
        GLDS16(gB1 + k0, lB1);
        __syncthreads();
        bf16x8 aF[4], bF[4];
#pragma unroll
        for (int m = 0; m < 4; ++m)
            aF[m] = *(const bf16x8*)&Alds[(wr * 64 + m * 16 + lo) * 32 + hi * 8];
#pragma unroll
        for (int n = 0; n < 4; ++n)
            bF[n] = *(const bf16x8*)&Blds[(wc * 64 + n * 16 + lo) * 32 + hi * 8];
#pragma unroll
        for (int m = 0; m < 4; ++m)
#pragma unroll
            for (int n = 0; n < 4; ++n)
                acc[m][n] = MFMA16(aF[m], bF[n], acc[m][n]);
        __syncthreads();
    }

    const int rbase = bm * 128 + wr * 64 + hi * 4;
    const int cbase = bn * 128 + wc * 64 + lo;
    if (MODE == 0) {
        bf16_t* C = (bf16_t*)Cout;
#pragma unroll
        for (int m = 0; m < 4; ++m)
#pragma unroll
            for (int n = 0; n < 4; ++n) {
                const int col = cbase + n * 16;
                const float bias = (col < 1024) ? b0[col]
                                 : (col < 2048) ? b1[col - 1024] : b2[col - 2048];
#pragma unroll
                for (int r = 0; r < 4; ++r) {
                    const int row = rbase + m * 16 + r;
                    C[(size_t)row * Ndim + col] = (bf16_t)(acc[m][n][r] + bias);
                }
            }
    } else {
        float* C = (float*)Cout;
#pragma unroll
        for (int m = 0; m < 4; ++m)
#pragma unroll
            for (int n = 0; n < 4; ++n) {
                const int col = cbase + n * 16;
                const float bias = b0[col];
#pragma unroll
                for (int r = 0; r < 4; ++r) {
                    const int row = rbase + m * 16 + r;
                    C[(size_t)row * Ndim + col] = acc[m][n][r] + bias;
                }
            }
    }
}

// ---------------------------------------------------------------------------
// K3: RoPE for Q,K + transpose to [BH][S][64]. K rows chunk-swizzled.
// ---------------------------------------------------------------------------
__global__ __launch_bounds__(256)
void rope_qk_kernel(const bf16_t* __restrict__ qkv,
                    const float* __restrict__ cosT,
                    const float* __restrict__ sinT,
                    bf16_t* __restrict__ Qr, bf16_t* __restrict__ Kr) {
    const int st = blockIdx.x, bh = blockIdx.y;
    const int b = bh >> 4, h = bh & 15;
    const int tid = threadIdx.x;
    const int r = tid >> 2;
    const int part = tid & 3;
    const int s = st * 64 + r;
    const int bs = b * kS + s;
    const bf16_t* qp = qkv + (size_t)bs * kNqkv + h * 64 + part * 16;
    const bf16_t* kp = qp + 1024;
    const size_t outoff = ((size_t)(b * kH + h) * kS + s) * 64;
    bf16_t* qo = Qr + outoff;
    char*   kob = (char*)(Kr + outoff);
    const float* cr = cosT + s * 32 + part * 8;
    const float* sr = sinT + s * 32 + part * 8;

    bf16x8 q0 = *(const bf16x8*)qp;
    bf16x8 q1 = *(const bf16x8*)(qp + 8);
    bf16x8 k0 = *(const bf16x8*)kp;
    bf16x8 k1 = *(const bf16x8*)(kp + 8);
    bf16x8 qlo, qhi, klo, khi;
#pragma unroll
    for (int j = 0; j < 8; ++j) {
        const float cv = cr[j];
        const float sv = sr[j];
        float qa, qb2, ka, kb2;
        if (j < 4) {
            qa = (float)q0[2 * j];     qb2 = (float)q0[2 * j + 1];
            ka = (float)k0[2 * j];     kb2 = (float)k0[2 * j + 1];
        } else {
            qa = (float)q1[2 * j - 8]; qb2 = (float)q1[2 * j - 7];
            ka = (float)k1[2 * j - 8]; kb2 = (float)k1[2 * j - 7];
        }
        qlo[j] = (bf16_t)(qa * cv - qb2 * sv);
        qhi[j] = (bf16_t)(qa * sv + qb2 * cv);
        klo[j] = (bf16_t)(ka * cv - kb2 * sv);
        khi[j] = (bf16_t)(ka * sv + kb2 * cv);
    }
    *(bf16x8*)(qo + part * 8)      = qlo;
    *(bf16x8*)(qo + 32 + part * 8) = qhi;
    const int sw = s & 7;
    *(bf16x8*)(kob + (((part)     ^ sw) << 4)) = klo;
    *(bf16x8*)(kob + (((part + 4) ^ sw) << 4)) = khi;
}

// ---------------------------------------------------------------------------
// K4: V transpose -> VT [BH][64][S], chunk-swizzled within each 64-col tile
// ---------------------------------------------------------------------------
__global__ void vtrans_kernel(const bf16_t* __restrict__ qkv, bf16_t* __restrict__ VT) {
    __shared__ __align__(16) bf16_t t[64 * 72];
    const int st = blockIdx.x, bh = blockIdx.y;
    const int b = bh >> 4, h = bh & 15;
    const int tid = threadIdx.x;
    const int r = tid >> 2, g = tid & 3;
    const bf16_t* src = qkv + ((size_t)(b * kS + st * 64 + r)) * kNqkv + 2048 + h * 64 + g * 16;
    bf16x8 v0 = *(const bf16x8*)src;
    bf16x8 v1 = *(const bf16x8*)(src + 8);
    *(bf16x8*)&t[r * 72 + g * 16] = v0;
    *(bf16x8*)&t[r * 72 + g * 16 + 8] = v1;
    __syncthreads();
    bf16x8 o0, o1;
#pragma unroll
    for (int j = 0; j < 8; ++j) {
        o0[j] = t[(g * 16 + j) * 72 + r];
        o1[j] = t[(g * 16 + 8 + j) * 72 + r];
    }
    char* dstb = (char*)(VT + ((size_t)bh * 64 + r) * kS) + st * 128;
    const int sw = r & 7;
    *(bf16x8*)(dstb + (((g * 2)     ^ sw) << 4)) = o0;
    *(bf16x8*)(dstb + (((g * 2 + 1) ^ sw) << 4)) = o1;
}

// ---------------------------------------------------------------------------
// K5: causal flash attention v3 — pair-folded for load balance.
// Block qp handles q-tiles qA=qp and qB=31-qp (64 rows each, 16/wave).
// Both stream the same staged KV tiles; exactly 792 MFMA per block.
// ---------------------------------------------------------------------------
__global__ __launch_bounds__(256, 2)
void attn_kernel(const bf16_t* __restrict__ Qr, const bf16_t* __restrict__ Kr,
                 const bf16_t* __restrict__ VT, bf16_t* __restrict__ attended) {
    __shared__ __align__(16) bf16_t Klds[2][64 * 64];
    __shared__ __align__(16) bf16_t Vlds[2][64 * 64];
    __shared__ __align__(16) bf16_t Plds[4][16 * 72];
    const int qp = blockIdx.x, bh = blockIdx.y;
    const int qA = qp, qB = 31 - qp;
    const int tid = threadIdx.x;
    const int lane = tid & 63, wid = tid >> 6;
    const int lo = lane & 15, hi = lane >> 4;
    const int q0A = qA * 64 + wid * 16;
    const int q0B = qB * 64 + wid * 16;

    const char* Kg = (const char*)(Kr + (size_t)bh * kS * 64);
    const char* Vg = (const char*)(VT + (size_t)bh * 64 * kS);
    const bf16_t* Q = Qr + (size_t)bh * kS * 64;

    const bf16x8 aQA0 = *(const bf16x8*)&Q[(size_t)(q0A + lo) * 64 + hi * 8];
    const bf16x8 aQA1 = *(const bf16x8*)&Q[(size_t)(q0A + lo) * 64 + 32 + hi * 8];
    const bf16x8 aQB0 = *(const bf16x8*)&Q[(size_t)(q0B + lo) * 64 + hi * 8];
    const bf16x8 aQB1 = *(const bf16x8*)&Q[(size_t)(q0B + lo) * 64 + 32 + hi * 8];

    bf16_t* Pl = &Plds[wid][0];

    f32x4 OA[4], OB[4];
#pragma unroll
    for (int dt = 0; dt < 4; ++dt) {
        OA[dt] = (f32x4){0.f, 0.f, 0.f, 0.f};
        OB[dt] = (f32x4){0.f, 0.f, 0.f, 0.f};
    }
    float mA[4], lA[4], mB[4], lB[4];
#pragma unroll
    for (int r = 0; r < 4; ++r) {
        mA[r] = -3e38f; lA[r] = 0.f;
        mB[r] = -3e38f; lB[r] = 0.f;
    }

    auto stage = [&](int buf, int t) {
        char* Kl = (char*)&Klds[buf][0];
        char* Vl = (char*)&Vlds[buf][0];
        const size_t kb = (size_t)t * 128 * 64;
        const int vcol = t * 128;
#pragma unroll
        for (int j = 0; j < 2; ++j) {
            const int seg = wid * 2 + j;
            GLDS16(Kg + kb + seg * 1024 + lane * 16, Kl + seg * 1024);
            const int row = seg * 8 + (lane >> 3);
            GLDS16(Vg + (size_t)row * (kS * 2) + vcol + (lane & 7) * 16, Vl + seg * 1024);
        }
    };

    const float kScale = 0.125f * 1.44269504f;

    // softmax + PV for one stream
    auto softmax_pv = [&](f32x4 (&sacc)[4], float (&m_run)[4], float (&l_run)[4],
                          f32x4 (&O)[4], int q0, bool edge, int kv0, const char* Vb) {
        float p[4][4];
        float pmax[4] = {-3e38f, -3e38f, -3e38f, -3e38f};
#pragma unroll
        for (int ct = 0; ct < 4; ++ct)
#pragma unroll
            for (int r = 0; r < 4; ++r) {
                float sv = sacc[ct][r] * kScale;
                if (edge && (kv0 + ct * 16 + lo > q0 + hi * 4 + r)) sv = -3e38f;
                p[ct][r] = sv;
                pmax[r] = fmaxf(pmax[r], sv);
            }
#pragma unroll
        for (int off = 1; off < 16; off <<= 1)
#pragma unroll
            for (int r = 0; r < 4; ++r)
                pmax[r] = fmaxf(pmax[r], __shfl_xor(pmax[r], off, 64));
        float alpha[4], psum[4];
#pragma unroll
        for (int r = 0; r < 4; ++r) {
            const float mn = fmaxf(m_run[r], pmax[r]);
            alpha[r] = exp2f(m_run[r] - mn);
            m_run[r] = mn;
            psum[r] = 0.f;
        }
#pragma unroll
        for (int ct = 0; ct < 4; ++ct)
#pragma unroll
            for (int r = 0; r < 4; ++r) {
                const float e = exp2f(p[ct][r] - m_run[r]);
                p[ct][r] = e;
                psum[r] += e;
            }
#pragma unroll
        for (int off = 1; off < 16; off <<= 1)
#pragma unroll
            for (int r = 0; r < 4; ++r)
                psum[r] += __shfl_xor(psum[r], off, 64);
#pragma unroll
        for (int r = 0; r < 4; ++r) l_run[r] = l_run[r] * alpha[r] + psum[r];
#pragma unroll
        for (int dt = 0; dt < 4; ++dt)
#pragma unroll
            for (int r = 0; r < 4; ++r) O[dt][r] *= alpha[r];
#pragma unroll
        for (int ct = 0; ct < 4; ++ct)
#pragma unroll
            for (int r = 0; r < 4; ++r)
                Pl[(hi * 4 + r) * 72 + ct * 16 + lo] = (bf16_t)p[ct][r];
        const bf16x8 aP0 = *(const bf16x8*)&Pl[lo * 72 + hi * 8];
        const bf16x8 aP1 = *(const bf16x8*)&Pl[lo * 72 + 32 + hi * 8];
#pragma unroll
        for (int dt = 0; dt < 4; ++dt) {
            const int rr = dt * 16 + lo;
            const bf16x8 bV0 = *(const bf16x8*)(Vb + rr * 128 + (((hi)     ^ (rr & 7)) << 4));
            const bf16x8 bV1 = *(const bf16x8*)(Vb + rr * 128 + (((hi + 4) ^ (rr & 7)) << 4));
            O[dt] = MFMA16(aP0, bV0, O[dt]);
            O[dt] = MFMA16(aP1, bV1, O[dt]);
        }
    };

    stage(0, 0);
    int cur = 0;
    for (int t = 0; t <= qB; ++t) {
        __syncthreads();
        if (t < qB) stage(cur ^ 1, t + 1);
        const char* Kb = (const char*)&Klds[cur][0];
        const char* Vb = (const char*)&Vlds[cur][0];
        const bool actA = (t <= qA);
        const int kv0 = t * 64;

        // QK^T for B (always) and A (overlap region)
        f32x4 sB[4], sA[4];
#pragma unroll
        for (int ct = 0; ct < 4; ++ct) {
            sB[ct] = (f32x4){0.f, 0.f, 0.f, 0.f};
            sA[ct] = (f32x4){0.f, 0.f, 0.f, 0.f};
        }
#pragma unroll
        for (int ct = 0; ct < 4; ++ct) {
            const int rr = ct * 16 + lo;
            const bf16x8 bK0 = *(const bf16x8*)(Kb + rr * 128 + (((hi)     ^ (rr & 7)) << 4));
            const bf16x8 bK1 = *(const bf16x8*)(Kb + rr * 128 + (((hi + 4) ^ (rr & 7)) << 4));
            sB[ct] = MFMA16(aQB0, bK0, sB[ct]);
            sB[ct] = MFMA16(aQB1, bK1, sB[ct]);
            if (actA) {
                sA[ct] = MFMA16(aQA0, bK0, sA[ct]);
                sA[ct] = MFMA16(aQA1, bK1, sA[ct]);
            }
        }

        if (actA) softmax_pv(sA, mA, lA, OA, q0A, t == qA, kv0, Vb);
        softmax_pv(sB, mB, lB, OB, q0B, t == qB, kv0, Vb);
        cur ^= 1;
    }

    // ---- epilogue ----
    const int b = bh >> 4, h = bh & 15;
    float invA[4], invB[4];
#pragma unroll
    for (int r = 0; r < 4; ++r) {
        invA[r] = 1.0f / lA[r];
        invB[r] = 1.0f / lB[r];
    }
#pragma unroll
    for (int dt = 0; dt < 4; ++dt)
#pragma unroll
        for (int r = 0; r < 4; ++r) {
            const int rowA = q0A + hi * 4 + r;
            const int rowB = q0B + hi * 4 + r;
            attended[((size_t)(b * kS + rowA)) * kD + h * 64 + dt * 16 + lo] =
                (bf16_t)(OA[dt][r] * invA[r]);
            attended[((size_t)(b * kS + rowB)) * kD + h * 64 + dt * 16 + lo] =
                (bf16_t)(OB[dt][r] * invB[r]);
        }
}

// ---------------------------------------------------------------------------
extern "C" void kernel_launch(void* const* d_in, const int* in_sizes, int n_in,
                              void* d_out, int out_size, void* d_ws, size_t ws_size,
                              hipStream_t stream) {
    const float* x  = (const float*)d_in[0];
    const float* Wq = (const float*)d_in[1];
    const float* bq = (const float*)d_in[2];
    const float* Wk = (const float*)d_in[3];
    const float* bk = (const float*)d_in[4];
    const float* Wv = (const float*)d_in[5];
    const float* bv = (const float*)d_in[6];
    const float* Wo = (const float*)d_in[7];
    const float* bo = (const float*)d_in[8];
    float* out = (float*)d_out;

    char* ws = (char*)d_ws;
    size_t off = 0;
    auto carve = [&](size_t bytes) -> char* {
        char* p = ws + off;
        off += (bytes + 255) & ~(size_t)255;
        return p;
    };
    bf16_t* xb    = (bf16_t*)carve((size_t)kM * kD * 2);
    bf16_t* WqkvT = (bf16_t*)carve((size_t)kNqkv * kD * 2);
    bf16_t* WoT   = (bf16_t*)carve((size_t)kD * kD * 2);
    float*  cosT  = (float*)carve((size_t)kS * 32 * 4);
    float*  sinT  = (float*)carve((size_t)kS * 32 * 4);
    bf16_t* qkv   = (bf16_t*)carve((size_t)kM * kNqkv * 2);
    bf16_t* Qr    = (bf16_t*)carve((size_t)kBH * kS * 64 * 2);
    bf16_t* Kr    = (bf16_t*)carve((size_t)kBH * kS * 64 * 2);
    bf16_t* VT    = (bf16_t*)carve((size_t)kBH * kS * 64 * 2);
    bf16_t* att   = (bf16_t*)carve((size_t)kM * kD * 2);

    cast_x_kernel<<<(kM * kD) / (256 * 4), 256, 0, stream>>>(x, xb);
    wtrans_kernel<<<dim3(32, 32), 256, 0, stream>>>(Wq, WqkvT);
    wtrans_kernel<<<dim3(32, 32), 256, 0, stream>>>(Wk, WqkvT + (size_t)1024 * 1024);
    wtrans_kernel<<<dim3(32, 32), 256, 0, stream>>>(Wv, WqkvT + (size_t)2048 * 1024);
    wtrans_kernel<<<dim3(32, 32), 256, 0, stream>>>(Wo, WoT);
    rope_table_kernel<<<(kS * 32) / 256, 256, 0, stream>>>(cosT, sinT);

    gemm_bf16<0><<<dim3(kM / 128, kNqkv / 128), 256, 0, stream>>>(
        xb, WqkvT, qkv, bq, bk, bv, kNqkv, kD);

    rope_qk_kernel<<<dim3(kS / 64, kBH), 256, 0, stream>>>(qkv, cosT, sinT, Qr, Kr);
    vtrans_kernel<<<dim3(kS / 64, kBH), 256, 0, stream>>>(qkv, VT);

    attn_kernel<<<dim3(kS / 128, kBH), 256, 0, stream>>>(Qr, Kr, VT, att);

    gemm_bf16<1><<<dim3(kM / 128, kD / 128), 256, 0, stream>>>(
        att, WoT, out, bo, nullptr, nullptr, kD, kD);
}

// Round 4
// 166.194 us; speedup vs baseline: 1.9421x; 1.0020x over previous
//
#include <hip/hip_runtime.h>
#include <hip/hip_bf16.h>

typedef __bf16 bf16_t;
typedef __bf16 bf16x4 __attribute__((ext_vector_type(4)));
typedef __bf16 bf16x8 __attribute__((ext_vector_type(8)));
typedef float  f32x4  __attribute__((ext_vector_type(4)));

#define GLDS16(gp, lp) __builtin_amdgcn_global_load_lds( \
    (const __attribute__((address_space(1))) void*)(gp), \
    (__attribute__((address_space(3))) void*)(lp), 16, 0, 0)

#define MFMA16(a, b, c) __builtin_amdgcn_mfma_f32_16x16x32_bf16((a), (b), (c), 0, 0, 0)

static constexpr int kB = 2, kS = 2048, kD = 1024, kH = 16, kL = 64;
static constexpr int kM = kB * kS;       // 4096 rows
static constexpr int kNqkv = 3 * kD;     // 3072
static constexpr int kBH = kB * kH;      // 32

// ---------------------------------------------------------------------------
// K1a: cast x f32 -> bf16
// ---------------------------------------------------------------------------
__global__ void cast_x_kernel(const float* __restrict__ x, bf16_t* __restrict__ xb) {
    int i = blockIdx.x * 256 + threadIdx.x;
    float4 v = ((const float4*)x)[i];
    bf16x4 o;
    o[0] = (bf16_t)v.x; o[1] = (bf16_t)v.y; o[2] = (bf16_t)v.z; o[3] = (bf16_t)v.w;
    ((bf16x4*)xb)[i] = o;
}

// ---------------------------------------------------------------------------
// K1b: transpose-cast a [1024][1024] f32 weight into bf16 [N][K] (B^T layout)
// ---------------------------------------------------------------------------
__global__ void wtrans_kernel(const float* __restrict__ W, bf16_t* __restrict__ Wt) {
    __shared__ float t[32 * 33];
    const int k0 = blockIdx.x * 32, n0 = blockIdx.y * 32;
    const int tid = threadIdx.x;
#pragma unroll
    for (int i = 0; i < 4; ++i) {
        int idx = i * 256 + tid;
        int r = idx >> 5, c = idx & 31;
        t[r * 33 + c] = W[(size_t)(k0 + r) * 1024 + n0 + c];
    }
    __syncthreads();
#pragma unroll
    for (int i = 0; i < 4; ++i) {
        int idx = i * 256 + tid;
        int r = idx >> 5, c = idx & 31;
        Wt[(size_t)(n0 + r) * 1024 + k0 + c] = (bf16_t)t[c * 33 + r];
    }
}

// ---------------------------------------------------------------------------
// K1c: RoPE cos/sin tables [S][32] f32
// ---------------------------------------------------------------------------
__global__ void rope_table_kernel(float* __restrict__ cosT, float* __restrict__ sinT) {
    int i = blockIdx.x * 256 + threadIdx.x;
    int s = i >> 5, j = i & 31;
    double inv = pow(10000.0, -2.0 * (double)j / 64.0);
    double ang = (double)s * inv;
    cosT[i] = (float)cos(ang);
    sinT[i] = (float)sin(ang);
}

// ---------------------------------------------------------------------------
// K2/K8: bf16 GEMM (m97 structure)
// ---------------------------------------------------------------------------
template <int MODE>
__global__ __launch_bounds__(256, 2)
void gemm_bf16(const bf16_t* __restrict__ A, const bf16_t* __restrict__ Bt,
               void* __restrict__ Cout,
               const float* __restrict__ b0, const float* __restrict__ b1,
               const float* __restrict__ b2, int Ndim, int Kdim) {
    __shared__ __align__(16) bf16_t Alds[128 * 32];
    __shared__ __align__(16) bf16_t Blds[128 * 32];
    const int tid = threadIdx.x;
    const int lane = tid & 63;
    const int wid = tid >> 6;
    const int lo = lane & 15, hi = lane >> 4;
    const int bm = blockIdx.x, bn = blockIdx.y;
    const int wr = wid >> 1, wc = wid & 1;

    const int rowS = (wid * 2) * 16 + (lane >> 2);
    const int colE = (lane & 3) * 8;
    const bf16_t* gA0 = A + (size_t)(bm * 128 + rowS) * Kdim + colE;
    const bf16_t* gA1 = gA0 + (size_t)16 * Kdim;
    const bf16_t* gB0 = Bt + (size_t)(bn * 128 + rowS) * Kdim + colE;
    const bf16_t* gB1 = gB0 + (size_t)16 * Kdim;
    bf16_t* lA0 = &Alds[(wid * 2) * 512];
    bf16_t* lA1 = &Alds[(wid * 2 + 1) * 512];
    bf16_t* lB0 = &Blds[(wid * 2) * 512];
    bf16_t* lB1 = &Blds[(wid * 2 + 1) * 512];

    f32x4 acc[4][4];
#pragma unroll
    for (int m = 0; m < 4; ++m)
#pragma unroll
        for (int n = 0; n < 4; ++n) acc[m][n] = (f32x4){0.f, 0.f, 0.f, 0.f};

    const int nk = Kdim >> 5;
    for (int kt = 0; kt < nk; ++kt) {
        const int k0 = kt * 32;
        GLDS16(gA0 + k0, lA0);
        GLDS16(gA1 + k0, lA1);
        GLDS16(gB0 + k0, lB0);
        GLDS16(gB1 + k0, lB1);
        __syncthreads();
        bf16x8 aF[4], bF[4];
#pragma unroll
        for (int m = 0; m < 4; ++m)
            aF[m] = *(const bf16x8*)&Alds[(wr * 64 + m * 16 + lo) * 32 + hi * 8];
#pragma unroll
        for (int n = 0; n < 4; ++n)
            bF[n] = *(const bf16x8*)&Blds[(wc * 64 + n * 16 + lo) * 32 + hi * 8];
#pragma unroll
        for (int m = 0; m < 4; ++m)
#pragma unroll
            for (int n = 0; n < 4; ++n)
                acc[m][n] = MFMA16(aF[m], bF[n], acc[m][n]);
        __syncthreads();
    }

    const int rbase = bm * 128 + wr * 64 + hi * 4;
    const int cbase = bn * 128 + wc * 64 + lo;
    if (MODE == 0) {
        bf16_t* C = (bf16_t*)Cout;
#pragma unroll
        for (int m = 0; m < 4; ++m)
#pragma unroll
            for (int n = 0; n < 4; ++n) {
                const int col = cbase + n * 16;
                const float bias = (col < 1024) ? b0[col]
                                 : (col < 2048) ? b1[col - 1024] : b2[col - 2048];
#pragma unroll
                for (int r = 0; r < 4; ++r) {
                    const int row = rbase + m * 16 + r;
                    C[(size_t)row * Ndim + col] = (bf16_t)(acc[m][n][r] + bias);
                }
            }
    } else {
        float* C = (float*)Cout;
#pragma unroll
        for (int m = 0; m < 4; ++m)
#pragma unroll
            for (int n = 0; n < 4; ++n) {
                const int col = cbase + n * 16;
                const float bias = b0[col];
#pragma unroll
                for (int r = 0; r < 4; ++r) {
                    const int row = rbase + m * 16 + r;
                    C[(size_t)row * Ndim + col] = acc[m][n][r] + bias;
                }
            }
    }
}

// ---------------------------------------------------------------------------
// K3: RoPE for Q,K + transpose to [BH][S][64]. K rows chunk-swizzled.
// ---------------------------------------------------------------------------
__global__ __launch_bounds__(256)
void rope_qk_kernel(const bf16_t* __restrict__ qkv,
                    const float* __restrict__ cosT,
                    const float* __restrict__ sinT,
                    bf16_t* __restrict__ Qr, bf16_t* __restrict__ Kr) {
    const int st = blockIdx.x, bh = blockIdx.y;
    const int b = bh >> 4, h = bh & 15;
    const int tid = threadIdx.x;
    const int r = tid >> 2;
    const int part = tid & 3;
    const int s = st * 64 + r;
    const int bs = b * kS + s;
    const bf16_t* qp = qkv + (size_t)bs * kNqkv + h * 64 + part * 16;
    const bf16_t* kp = qp + 1024;
    const size_t outoff = ((size_t)(b * kH + h) * kS + s) * 64;
    bf16_t* qo = Qr + outoff;
    char*   kob = (char*)(Kr + outoff);
    const float* cr = cosT + s * 32 + part * 8;
    const float* sr = sinT + s * 32 + part * 8;

    bf16x8 q0 = *(const bf16x8*)qp;
    bf16x8 q1 = *(const bf16x8*)(qp + 8);
    bf16x8 k0 = *(const bf16x8*)kp;
    bf16x8 k1 = *(const bf16x8*)(kp + 8);
    bf16x8 qlo, qhi, klo, khi;
#pragma unroll
    for (int j = 0; j < 8; ++j) {
        const float cv = cr[j];
        const float sv = sr[j];
        float qa, qb2, ka, kb2;
        if (j < 4) {
            qa = (float)q0[2 * j];     qb2 = (float)q0[2 * j + 1];
            ka = (float)k0[2 * j];     kb2 = (float)k0[2 * j + 1];
        } else {
            qa = (float)q1[2 * j - 8]; qb2 = (float)q1[2 * j - 7];
            ka = (float)k1[2 * j - 8]; kb2 = (float)k1[2 * j - 7];
        }
        qlo[j] = (bf16_t)(qa * cv - qb2 * sv);
        qhi[j] = (bf16_t)(qa * sv + qb2 * cv);
        klo[j] = (bf16_t)(ka * cv - kb2 * sv);
        khi[j] = (bf16_t)(ka * sv + kb2 * cv);
    }
    *(bf16x8*)(qo + part * 8)      = qlo;
    *(bf16x8*)(qo + 32 + part * 8) = qhi;
    const int sw = s & 7;
    *(bf16x8*)(kob + (((part)     ^ sw) << 4)) = klo;
    *(bf16x8*)(kob + (((part + 4) ^ sw) << 4)) = khi;
}

// ---------------------------------------------------------------------------
// K4: V transpose -> VT [BH][64][S], chunk-swizzled within each 64-col tile
// ---------------------------------------------------------------------------
__global__ void vtrans_kernel(const bf16_t* __restrict__ qkv, bf16_t* __restrict__ VT) {
    __shared__ __align__(16) bf16_t t[64 * 72];
    const int st = blockIdx.x, bh = blockIdx.y;
    const int b = bh >> 4, h = bh & 15;
    const int tid = threadIdx.x;
    const int r = tid >> 2, g = tid & 3;
    const bf16_t* src = qkv + ((size_t)(b * kS + st * 64 + r)) * kNqkv + 2048 + h * 64 + g * 16;
    bf16x8 v0 = *(const bf16x8*)src;
    bf16x8 v1 = *(const bf16x8*)(src + 8);
    *(bf16x8*)&t[r * 72 + g * 16] = v0;
    *(bf16x8*)&t[r * 72 + g * 16 + 8] = v1;
    __syncthreads();
    bf16x8 o0, o1;
#pragma unroll
    for (int j = 0; j < 8; ++j) {
        o0[j] = t[(g * 16 + j) * 72 + r];
        o1[j] = t[(g * 16 + 8 + j) * 72 + r];
    }
    char* dstb = (char*)(VT + ((size_t)bh * 64 + r) * kS) + st * 128;
    const int sw = r & 7;
    *(bf16x8*)(dstb + (((g * 2)     ^ sw) << 4)) = o0;
    *(bf16x8*)(dstb + (((g * 2 + 1) ^ sw) << 4)) = o1;
}

// ---------------------------------------------------------------------------
// K5: causal flash attention v4 — pair-folded + half-split for occupancy.
// Block (pair, half): q-tiles qA=pair, qB=31-pair; rows [half*32, half*32+32)
// of each (16 per wave). 2 waves/block, ~34 KB LDS -> 4 blocks/CU.
// ---------------------------------------------------------------------------
__global__ __launch_bounds__(128, 2)
void attn_kernel(const bf16_t* __restrict__ Qr, const bf16_t* __restrict__ Kr,
                 const bf16_t* __restrict__ VT, bf16_t* __restrict__ attended) {
    __shared__ __align__(16) bf16_t Klds[2][64 * 64];
    __shared__ __align__(16) bf16_t Vlds[2][64 * 64];
    __shared__ __align__(16) bf16_t Plds[2][16 * 72];
    const int pair = blockIdx.x >> 1, half = blockIdx.x & 1;
    const int bh = blockIdx.y;
    const int qA = pair, qB = 31 - pair;
    const int tid = threadIdx.x;
    const int lane = tid & 63, wid = tid >> 6;     // wid in {0,1}
    const int lo = lane & 15, hi = lane >> 4;
    const int q0A = qA * 64 + half * 32 + wid * 16;
    const int q0B = qB * 64 + half * 32 + wid * 16;

    const char* Kg = (const char*)(Kr + (size_t)bh * kS * 64);
    const char* Vg = (const char*)(VT + (size_t)bh * 64 * kS);
    const bf16_t* Q = Qr + (size_t)bh * kS * 64;

    const bf16x8 aQA0 = *(const bf16x8*)&Q[(size_t)(q0A + lo) * 64 + hi * 8];
    const bf16x8 aQA1 = *(const bf16x8*)&Q[(size_t)(q0A + lo) * 64 + 32 + hi * 8];
    const bf16x8 aQB0 = *(const bf16x8*)&Q[(size_t)(q0B + lo) * 64 + hi * 8];
    const bf16x8 aQB1 = *(const bf16x8*)&Q[(size_t)(q0B + lo) * 64 + 32 + hi * 8];

    bf16_t* Pl = &Plds[wid][0];

    f32x4 OA[4], OB[4];
#pragma unroll
    for (int dt = 0; dt < 4; ++dt) {
        OA[dt] = (f32x4){0.f, 0.f, 0.f, 0.f};
        OB[dt] = (f32x4){0.f, 0.f, 0.f, 0.f};
    }
    float mA[4], lA[4], mB[4], lB[4];
#pragma unroll
    for (int r = 0; r < 4; ++r) {
        mA[r] = -3e38f; lA[r] = 0.f;
        mB[r] = -3e38f; lB[r] = 0.f;
    }

    auto stage = [&](int buf, int t) {
        char* Kl = (char*)&Klds[buf][0];
        char* Vl = (char*)&Vlds[buf][0];
        const size_t kb = (size_t)t * 128 * 64;
        const int vcol = t * 128;
#pragma unroll
        for (int j = 0; j < 4; ++j) {
            const int seg = wid * 4 + j;          // 1KB segments, 8 per tile
            GLDS16(Kg + kb + seg * 1024 + lane * 16, Kl + seg * 1024);
            const int row = seg * 8 + (lane >> 3);
            GLDS16(Vg + (size_t)row * (kS * 2) + vcol + (lane & 7) * 16, Vl + seg * 1024);
        }
    };

    const float kScale = 0.125f * 1.44269504f;

    // softmax + PV for one stream (T13 defer-max, log2 domain, THR=8)
    auto softmax_pv = [&](f32x4 (&sacc)[4], float (&m_run)[4], float (&l_run)[4],
                          f32x4 (&O)[4], int q0, bool edge, int kv0, const char* Vb) {
        float p[4][4];
        float pmax[4] = {-3e38f, -3e38f, -3e38f, -3e38f};
#pragma unroll
        for (int ct = 0; ct < 4; ++ct)
#pragma unroll
            for (int r = 0; r < 4; ++r) {
                float sv = sacc[ct][r] * kScale;
                if (edge && (kv0 + ct * 16 + lo > q0 + hi * 4 + r)) sv = -3e38f;
                p[ct][r] = sv;
                pmax[r] = fmaxf(pmax[r], sv);
            }
#pragma unroll
        for (int off = 1; off < 16; off <<= 1)
#pragma unroll
            for (int r = 0; r < 4; ++r)
                pmax[r] = fmaxf(pmax[r], __shfl_xor(pmax[r], off, 64));
        float dmax = -3e38f;
#pragma unroll
        for (int r = 0; r < 4; ++r) dmax = fmaxf(dmax, pmax[r] - m_run[r]);
        if (!__all(dmax <= 8.0f)) {
            float alpha[4];
#pragma unroll
            for (int r = 0; r < 4; ++r) {
                const float mn = fmaxf(m_run[r], pmax[r]);
                alpha[r] = exp2f(m_run[r] - mn);
                m_run[r] = mn;
                l_run[r] *= alpha[r];
            }
#pragma unroll
            for (int dt = 0; dt < 4; ++dt)
#pragma unroll
                for (int r = 0; r < 4; ++r) O[dt][r] *= alpha[r];
        }
        float psum[4] = {0.f, 0.f, 0.f, 0.f};
#pragma unroll
        for (int ct = 0; ct < 4; ++ct)
#pragma unroll
            for (int r = 0; r < 4; ++r) {
                const float e = exp2f(p[ct][r] - m_run[r]);
                p[ct][r] = e;
                psum[r] += e;
            }
#pragma unroll
        for (int off = 1; off < 16; off <<= 1)
#pragma unroll
            for (int r = 0; r < 4; ++r)
                psum[r] += __shfl_xor(psum[r], off, 64);
#pragma unroll
        for (int r = 0; r < 4; ++r) l_run[r] += psum[r];
#pragma unroll
        for (int ct = 0; ct < 4; ++ct)
#pragma unroll
            for (int r = 0; r < 4; ++r)
                Pl[(hi * 4 + r) * 72 + ct * 16 + lo] = (bf16_t)p[ct][r];
        const bf16x8 aP0 = *(const bf16x8*)&Pl[lo * 72 + hi * 8];
        const bf16x8 aP1 = *(const bf16x8*)&Pl[lo * 72 + 32 + hi * 8];
#pragma unroll
        for (int dt = 0; dt < 4; ++dt) {
            const int rr = dt * 16 + lo;
            const bf16x8 bV0 = *(const bf16x8*)(Vb + rr * 128 + (((hi)     ^ (rr & 7)) << 4));
            const bf16x8 bV1 = *(const bf16x8*)(Vb + rr * 128 + (((hi + 4) ^ (rr & 7)) << 4));
            O[dt] = MFMA16(aP0, bV0, O[dt]);
            O[dt] = MFMA16(aP1, bV1, O[dt]);
        }
    };

    stage(0, 0);
    int cur = 0;
    for (int t = 0; t <= qB; ++t) {
        __syncthreads();
        if (t < qB) stage(cur ^ 1, t + 1);
        const char* Kb = (const char*)&Klds[cur][0];
        const char* Vb = (const char*)&Vlds[cur][0];
        const bool actA = (t <= qA);
        const int kv0 = t * 64;

        f32x4 sB[4], sA[4];
#pragma unroll
        for (int ct = 0; ct < 4; ++ct) {
            sB[ct] = (f32x4){0.f, 0.f, 0.f, 0.f};
            sA[ct] = (f32x4){0.f, 0.f, 0.f, 0.f};
        }
#pragma unroll
        for (int ct = 0; ct < 4; ++ct) {
            const int rr = ct * 16 + lo;
            const bf16x8 bK0 = *(const bf16x8*)(Kb + rr * 128 + (((hi)     ^ (rr & 7)) << 4));
            const bf16x8 bK1 = *(const bf16x8*)(Kb + rr * 128 + (((hi + 4) ^ (rr & 7)) << 4));
            sB[ct] = MFMA16(aQB0, bK0, sB[ct]);
            sB[ct] = MFMA16(aQB1, bK1, sB[ct]);
            if (actA) {
                sA[ct] = MFMA16(aQA0, bK0, sA[ct]);
                sA[ct] = MFMA16(aQA1, bK1, sA[ct]);
            }
        }

        if (actA) softmax_pv(sA, mA, lA, OA, q0A, t == qA, kv0, Vb);
        softmax_pv(sB, mB, lB, OB, q0B, t == qB, kv0, Vb);
        cur ^= 1;
    }

    // ---- epilogue ----
    const int b = bh >> 4, h = bh & 15;
    float invA[4], invB[4];
#pragma unroll
    for (int r = 0; r < 4; ++r) {
        invA[r] = 1.0f / lA[r];
        invB[r] = 1.0f / lB[r];
    }
#pragma unroll
    for (int dt = 0; dt < 4; ++dt)
#pragma unroll
        for (int r = 0; r < 4; ++r) {
            const int rowA = q0A + hi * 4 + r;
            const int rowB = q0B + hi * 4 + r;
            attended[((size_t)(b * kS + rowA)) * kD + h * 64 + dt * 16 + lo] =
                (bf16_t)(OA[dt][r] * invA[r]);
            attended[((size_t)(b * kS + rowB)) * kD + h * 64 + dt * 16 + lo] =
                (bf16_t)(OB[dt][r] * invB[r]);
        }
}

// ---------------------------------------------------------------------------
extern "C" void kernel_launch(void* const* d_in, const int* in_sizes, int n_in,
                              void* d_out, int out_size, void* d_ws, size_t ws_size,
                              hipStream_t stream) {
    const float* x  = (const float*)d_in[0];
    const float* Wq = (const float*)d_in[1];
    const float* bq = (const float*)d_in[2];
    const float* Wk = (const float*)d_in[3];
    const float* bk = (const float*)d_in[4];
    const float* Wv = (const float*)d_in[5];
    const float* bv = (const float*)d_in[6];
    const float* Wo = (const float*)d_in[7];
    const float* bo = (const float*)d_in[8];
    float* out = (float*)d_out;

    char* ws = (char*)d_ws;
    size_t off = 0;
    auto carve = [&](size_t bytes) -> char* {
        char* p = ws + off;
        off += (bytes + 255) & ~(size_t)255;
        return p;
    };
    bf16_t* xb    = (bf16_t*)carve((size_t)kM * kD * 2);
    bf16_t* WqkvT = (bf16_t*)carve((size_t)kNqkv * kD * 2);
    bf16_t* WoT   = (bf16_t*)carve((size_t)kD * kD * 2);
    float*  cosT  = (float*)carve((size_t)kS * 32 * 4);
    float*  sinT  = (float*)carve((size_t)kS * 32 * 4);
    bf16_t* qkv   = (bf16_t*)carve((size_t)kM * kNqkv * 2);
    bf16_t* Qr    = (bf16_t*)carve((size_t)kBH * kS * 64 * 2);
    bf16_t* Kr    = (bf16_t*)carve((size_t)kBH * kS * 64 * 2);
    bf16_t* VT    = (bf16_t*)carve((size_t)kBH * kS * 64 * 2);
    bf16_t* att   = (bf16_t*)carve((size_t)kM * kD * 2);

    cast_x_kernel<<<(kM * kD) / (256 * 4), 256, 0, stream>>>(x, xb);
    wtrans_kernel<<<dim3(32, 32), 256, 0, stream>>>(Wq, WqkvT);
    wtrans_kernel<<<dim3(32, 32), 256, 0, stream>>>(Wk, WqkvT + (size_t)1024 * 1024);
    wtrans_kernel<<<dim3(32, 32), 256, 0, stream>>>(Wv, WqkvT + (size_t)2048 * 1024);
    wtrans_kernel<<<dim3(32, 32), 256, 0, stream>>>(Wo, WoT);
    rope_table_kernel<<<(kS * 32) / 256, 256, 0, stream>>>(cosT, sinT);

    gemm_bf16<0><<<dim3(kM / 128, kNqkv / 128), 256, 0, stream>>>(
        xb, WqkvT, qkv, bq, bk, bv, kNqkv, kD);

    rope_qk_kernel<<<dim3(kS / 64, kBH), 256, 0, stream>>>(qkv, cosT, sinT, Qr, Kr);
    vtrans_kernel<<<dim3(kS / 64, kBH), 256, 0, stream>>>(qkv, VT);

    attn_kernel<<<dim3(32, kBH), 128, 0, stream>>>(Qr, Kr, VT, att);

    gemm_bf16<1><<<dim3(kM / 128, kD / 128), 256, 0, stream>>>(
        att, WoT, out, bo, nullptr, nullptr, kD, kD);
}